// Round 9
// baseline (80.252 us; speedup 1.0000x reference)
//
#include <hip/hip_runtime.h>
#include <hip/hip_bf16.h>

#define NN 7
#define HH 16
#define RR 64
#define CC 8
#define NBINS (NN * RR * NN)   // 3136

#define HIST_BLOCK 1024
#define HIST_GRID  256                      // 1 block/CU -> all blocks co-resident
#define NT (HIST_GRID * HIST_BLOCK)         // 262144 threads
#define RED_BLOCKS 49                       // 49*64 = 3136 bins
#define MAGIC 0x13579BDF

// ctrl word offsets (separate cache lines)
#define C_CNT1  0
#define C_CNT2  16
#define C_READY 32

// One phase of the barrage: 12 dwordx4 loads back-to-back (clamped), then 16
// predicated LDS atomics. START selects slot group {0-3} or {4-7}.
#define PHASE(START)                                                         \
    {                                                                        \
        const int base_ = tid + (START);                                     \
        int4 S[4], D[4], T[4];                                               \
        _Pragma("unroll")                                                    \
        for (int k = 0; k < 4; ++k) {                                        \
            int idx = base_ + k * NT;                                        \
            int cl = idx < E4 ? idx : (E4 - 1);                              \
            S[k] = s4[cl]; D[k] = d4[cl]; T[k] = t4[cl];                     \
        }                                                                    \
        _Pragma("unroll")                                                    \
        for (int k = 0; k < 4; ++k) {                                        \
            const int add = (base_ + k * NT < E4) ? 1 : 0;                   \
            atomicAdd(&bins[D[k].x * (RR * NN) + T[k].x * NN + S[k].x], add);\
            atomicAdd(&bins[D[k].y * (RR * NN) + T[k].y * NN + S[k].y], add);\
            atomicAdd(&bins[D[k].z * (RR * NN) + T[k].z * NN + S[k].z], add);\
            atomicAdd(&bins[D[k].w * (RR * NN) + T[k].w * NN + S[k].w], add);\
        }                                                                    \
    }

__global__ __launch_bounds__(HIST_BLOCK) void rgcn_fused(
    const int* __restrict__ src, const int* __restrict__ dst,
    const int* __restrict__ et, int E,
    const float* __restrict__ W1,    // [R][N][H]
    const float* __restrict__ root1, // [N][H]
    const float* __restrict__ b1,    // [H]
    const float* __restrict__ W2,    // [R][H][C]
    const float* __restrict__ root2, // [H][C]
    const float* __restrict__ b2,    // [C]
    float* __restrict__ out,         // [N][C]
    int* __restrict__ part, int* __restrict__ gbins, int* __restrict__ ctrl) {
    __shared__ int   bins[NBINS];       // hist bins; reused as reduce scratch
    __shared__ float cntf[NN][RR][NN];
    __shared__ float p1[NN][HH][4];
    __shared__ float h[NN][HH];
    __shared__ float hr[NN][RR][CC];
    __shared__ float p2[NN][CC][8];
    __shared__ float o[NN][CC];
    __shared__ int   lastflag;

    const int t = threadIdx.x;
    const int b = blockIdx.x;

    // Block 0 re-arms the control block each call (robust to 0xAA poison:
    // nobody touches counters before observing READY==MAGIC).
    if (b == 0 && t == 0) {
        __hip_atomic_store(&ctrl[C_CNT1], 0, __ATOMIC_RELAXED, __HIP_MEMORY_SCOPE_AGENT);
        __hip_atomic_store(&ctrl[C_CNT2], 0, __ATOMIC_RELAXED, __HIP_MEMORY_SCOPE_AGENT);
        __hip_atomic_store(&ctrl[C_READY], MAGIC, __ATOMIC_RELEASE, __HIP_MEMORY_SCOPE_AGENT);
    }

    // ---- hist phase (R8's proven depth-4 barrage, wave-desynced) ----
    for (int i = t; i < NBINS; i += HIST_BLOCK) bins[i] = 0;
    __syncthreads();

    const int tid = b * HIST_BLOCK + t;
    const int E4 = E >> 2;
    const int4* s4 = reinterpret_cast<const int4*>(src);
    const int4* d4 = reinterpret_cast<const int4*>(dst);
    const int4* t4 = reinterpret_cast<const int4*>(et);

    if (E4 > 0) {
        // odd waves do slots {4-7} first so load/atomic phases interleave
        const int first = ((t >> 6) & 1) ? (4 * NT) : 0;
        for (int off = 0; off < E4; off += 8 * NT) {
            PHASE(off + first)
            PHASE(off + (4 * NT) - first)
        }
    }
    // scalar tail (E not multiple of 4; never runs for E=8M)
    for (int e = (E4 << 2) + tid; e < E; e += NT) {
        atomicAdd(&bins[dst[e] * (RR * NN) + et[e] * NN + src[e]], 1);
    }
    __syncthreads();

    // store block-private histogram, vectorized (784 int4)
    int4* slice4 = reinterpret_cast<int4*>(part + b * NBINS);
    const int4* bins4 = reinterpret_cast<const int4*>(bins);
    for (int i = t; i < NBINS / 4; i += HIST_BLOCK) slice4[i] = bins4[i];
    __syncthreads();

    // ---- grid barrier (device-scope atomics; all blocks co-resident) ----
    if (t == 0) {
        while (__hip_atomic_load(&ctrl[C_READY], __ATOMIC_ACQUIRE,
                                 __HIP_MEMORY_SCOPE_AGENT) != MAGIC)
            __builtin_amdgcn_s_sleep(8);
        __threadfence();
        __hip_atomic_fetch_add(&ctrl[C_CNT1], 1, __ATOMIC_ACQ_REL,
                               __HIP_MEMORY_SCOPE_AGENT);
    }
    if (b >= RED_BLOCKS) return;   // 207 blocks done

    if (t == 0) {
        while (__hip_atomic_load(&ctrl[C_CNT1], __ATOMIC_ACQUIRE,
                                 __HIP_MEMORY_SCOPE_AGENT) < HIST_GRID)
            __builtin_amdgcn_s_sleep(8);
    }
    __syncthreads();
    __threadfence();

    // ---- reduce phase: this block owns bins [b*64, b*64+64) ----
    {
        const int binl = t & 63;
        const int chunk = t >> 6;            // 0..15
        const int gbin = b * 64 + binl;
        int s = 0;
#pragma unroll
        for (int k = 0; k < 16; ++k)
            s += part[(chunk * 16 + k) * NBINS + gbin];
        bins[chunk * 64 + binl] = s;         // reuse LDS
    }
    __syncthreads();
    if (t < 64) {
        int tot = 0;
#pragma unroll
        for (int c = 0; c < 16; ++c) tot += bins[c * 64 + t];
        gbins[b * 64 + t] = tot;
    }
    __threadfence();
    __syncthreads();
    if (t == 0) {
        int old = __hip_atomic_fetch_add(&ctrl[C_CNT2], 1, __ATOMIC_ACQ_REL,
                                         __HIP_MEMORY_SCOPE_AGENT);
        lastflag = (old == RED_BLOCKS - 1) ? 1 : 0;
    }
    __syncthreads();
    if (!lastflag) return;         // 48 blocks done; last block finishes
    __threadfence();               // acquire all gbins

    // ---- finish phase (1024 threads; weights via L1/L2) ----
    const int BD = HIST_BLOCK;
    for (int i = t; i < NN * RR; i += BD) {
        int n = i / RR, r = i % RR;
        const int* gb = gbins + n * (RR * NN) + r * NN;
        int c[NN];
        int tot = 0;
#pragma unroll
        for (int s = 0; s < NN; ++s) { c[s] = gb[s]; tot += c[s]; }
        float inv = 1.0f / (float)(tot > 0 ? tot : 1);
#pragma unroll
        for (int s = 0; s < NN; ++s) cntf[n][r][s] = (float)c[s] * inv;
    }
    __syncthreads();

    // layer 1 partials: (n,j,q), q sums r in [16q,16q+16)
    for (int i = t; i < NN * HH * 4; i += BD) {
        int n = i >> 6;
        int j = (i >> 2) & (HH - 1);
        int q = i & 3;
        float acc = 0.0f;
        for (int r = q * 16; r < q * 16 + 16; ++r)
            for (int s = 0; s < NN; ++s)
                acc = fmaf(cntf[n][r][s], W1[(r * NN + s) * HH + j], acc);
        p1[n][j][q] = acc;
    }
    __syncthreads();
    for (int i = t; i < NN * HH; i += BD) {
        int n = i / HH, j = i % HH;
        float acc = root1[n * HH + j] + b1[j] +
                    p1[n][j][0] + p1[n][j][1] + p1[n][j][2] + p1[n][j][3];
        h[n][j] = fmaxf(acc, 0.0f);
    }
    __syncthreads();

    // hr[s][r][c] = sum_j h[s][j] * W2[r][j][c]
    for (int i = t; i < NN * RR * CC; i += BD) {
        int s = i / (RR * CC);
        int rem = i % (RR * CC);
        int r = rem / CC, c = rem % CC;
        float acc = 0.0f;
        for (int j = 0; j < HH; ++j)
            acc = fmaf(h[s][j], W2[(r * HH + j) * CC + c], acc);
        hr[s][r][c] = acc;
    }
    __syncthreads();

    // layer 2 partials: (n,c,q), q sums r in [8q,8q+8); q==0 adds root+bias
    for (int i = t; i < NN * CC * 8; i += BD) {
        int n = i >> 6;
        int c = (i >> 3) & (CC - 1);
        int q = i & 7;
        float acc = 0.0f;
        for (int r = q * 8; r < q * 8 + 8; ++r)
            for (int s = 0; s < NN; ++s)
                acc = fmaf(cntf[n][r][s], hr[s][r][c], acc);
        if (q == 0) {
            for (int j = 0; j < HH; ++j)
                acc = fmaf(h[n][j], root2[j * CC + c], acc);
            acc += b2[c];
        }
        p2[n][c][q] = acc;
    }
    __syncthreads();
    for (int i = t; i < NN * CC; i += BD) {
        int n = i / CC, c = i % CC;
        float acc = 0.0f;
        for (int q = 0; q < 8; ++q) acc += p2[n][c][q];
        o[n][c] = acc;
    }
    __syncthreads();

    // row-wise log_softmax
    if (t < NN) {
        float m = -1e30f;
        for (int c = 0; c < CC; ++c) m = fmaxf(m, o[t][c]);
        float sum = 0.0f;
        for (int c = 0; c < CC; ++c) sum += __expf(o[t][c] - m);
        float lse = m + __logf(sum);
        for (int c = 0; c < CC; ++c) out[t * CC + c] = o[t][c] - lse;
    }
    __syncthreads();
    // disarm READY so the next call re-arms counters race-free
    if (t == 0)
        __hip_atomic_store(&ctrl[C_READY], 0, __ATOMIC_RELEASE,
                           __HIP_MEMORY_SCOPE_AGENT);
}

extern "C" void kernel_launch(void* const* d_in, const int* in_sizes, int n_in,
                              void* d_out, int out_size, void* d_ws, size_t ws_size,
                              hipStream_t stream) {
    // input order: x, edge_index, edge_type, W1, root1, b1, W2, root2, b2
    const int* edge_index = (const int*)d_in[1];
    const int* edge_type  = (const int*)d_in[2];
    const float* W1    = (const float*)d_in[3];
    const float* root1 = (const float*)d_in[4];
    const float* b1    = (const float*)d_in[5];
    const float* W2    = (const float*)d_in[6];
    const float* root2 = (const float*)d_in[7];
    const float* b2    = (const float*)d_in[8];
    float* out = (float*)d_out;

    const int E = in_sizes[2];              // num edges
    const int* src = edge_index;            // edge_index[0]
    const int* dst = edge_index + E;        // edge_index[1]

    int* part  = (int*)d_ws;                       // 256*3136 ints = 3.2 MB
    int* gbins = part + HIST_GRID * NBINS;         // 3136 ints
    int* ctrl  = gbins + NBINS;                    // 64 ints control block

    rgcn_fused<<<HIST_GRID, HIST_BLOCK, 0, stream>>>(
        src, dst, edge_type, E, W1, root1, b1, W2, root2, b2, out,
        part, gbins, ctrl);
}

// Round 10
// 37.559 us; speedup vs baseline: 2.1367x; 2.1367x over previous
//
#include <hip/hip_runtime.h>
#include <hip/hip_bf16.h>

#define NN 7
#define HH 16
#define RR 64
#define CC 8
#define NBINS (NN * RR * NN)   // 3136

#define HIST_BLOCK 1024
#define HIST_GRID  256                      // 1 block/CU, 16 waves/CU, 128-VGPR budget
#define NT (HIST_GRID * HIST_BLOCK)         // 262144 threads
#define NSLOT 8                             // ceil(E4/NT) = 8 for E=8M

// ---------------------------------------------------------------------------
// Kernel 1: histogram edges into (dst, rel, src) bins in LDS.
// Rolling depth-4 software pipeline over 8 slots: prologue issues 12 loads
// (slots 0-3); each unrolled step does {16 predicated LDS atomics for slot k,
// then reissues slot k+4's 3 loads into the same registers}. In-flight loads
// never drain to zero (AITER vmcnt pattern) — unlike R8's phase-synchronous
// {12 loads -> drain -> 16 atomics} x2 which idled the memory pipe during
// every atomic phase. All slot indices compile-time (no scratch).
// ---------------------------------------------------------------------------
__global__ __launch_bounds__(HIST_BLOCK) void rgcn_hist(
    const int* __restrict__ src, const int* __restrict__ dst,
    const int* __restrict__ et, int E, int* __restrict__ part) {
    __shared__ int bins[NBINS];
    for (int i = threadIdx.x; i < NBINS; i += HIST_BLOCK) bins[i] = 0;
    __syncthreads();

    const int tid = blockIdx.x * HIST_BLOCK + threadIdx.x;
    const int E4 = E >> 2;
    const int4* s4 = reinterpret_cast<const int4*>(src);
    const int4* d4 = reinterpret_cast<const int4*>(dst);
    const int4* t4 = reinterpret_cast<const int4*>(et);

    if (E4 > 0) {
        for (int base = tid; base < E4; base += NSLOT * NT) {
            int4 S[4], D[4], T[4];
            // prologue: 12 loads back-to-back (slots 0-3, clamped)
#pragma unroll
            for (int k = 0; k < 4; ++k) {
                int idx = base + k * NT;
                int cl = idx < E4 ? idx : (E4 - 1);
                S[k] = s4[cl]; D[k] = d4[cl]; T[k] = t4[cl];
            }
            // steady state: consume slot k, reissue slot k+4 into same regs
#pragma unroll
            for (int k = 0; k < NSLOT; ++k) {
                const int slot = k & 3;
                const int add = (base + k * NT < E4) ? 1 : 0;  // predicate OOB
                atomicAdd(&bins[D[slot].x * (RR * NN) + T[slot].x * NN + S[slot].x], add);
                atomicAdd(&bins[D[slot].y * (RR * NN) + T[slot].y * NN + S[slot].y], add);
                atomicAdd(&bins[D[slot].z * (RR * NN) + T[slot].z * NN + S[slot].z], add);
                atomicAdd(&bins[D[slot].w * (RR * NN) + T[slot].w * NN + S[slot].w], add);
                if (k < NSLOT - 4) {
                    int idx = base + (k + 4) * NT;
                    int cl = idx < E4 ? idx : (E4 - 1);
                    S[slot] = s4[cl]; D[slot] = d4[cl]; T[slot] = t4[cl];
                }
            }
        }
    }
    // scalar tail (E not multiple of 4; never runs for E=8M)
    for (int e = (E4 << 2) + tid; e < E; e += NT) {
        atomicAdd(&bins[dst[e] * (RR * NN) + et[e] * NN + src[e]], 1);
    }

    __syncthreads();
    // plain coalesced store of the whole private histogram, vectorized
    int4* slice4 = reinterpret_cast<int4*>(part + blockIdx.x * NBINS);
    const int4* bins4 = reinterpret_cast<const int4*>(bins);
    for (int i2 = threadIdx.x; i2 < NBINS / 4; i2 += HIST_BLOCK)
        slice4[i2] = bins4[i2];
}

// ---------------------------------------------------------------------------
// Kernel 1b: reduce HIST_GRID partial histograms -> gbins. 49 blocks x 256
// threads; each block owns 64 bins; 4 chunks of HIST_GRID/4 partials per bin.
// Integer sums, fixed order -> deterministic & exact.
// ---------------------------------------------------------------------------
__global__ __launch_bounds__(256) void rgcn_reduce(
    const int* __restrict__ part, int* __restrict__ gbins) {
    __shared__ int acc[4][64];
    const int lane = threadIdx.x & 63;
    const int chunk = threadIdx.x >> 6;      // 0..3
    const int bin = blockIdx.x * 64 + lane;  // 49*64 = 3136 exactly

    int s = 0;
    const int p0 = chunk * (HIST_GRID / 4);
#pragma unroll 8
    for (int k = 0; k < HIST_GRID / 4; ++k)
        s += part[(p0 + k) * NBINS + bin];
    acc[chunk][lane] = s;
    __syncthreads();
    if (chunk == 0)
        gbins[bin] = acc[0][lane] + acc[1][lane] + acc[2][lane] + acc[3][lane];
}

// ---------------------------------------------------------------------------
// Kernel 2: everything else, single block of 1024. W1/W2 staged into LDS;
// cntf computed directly from gbins. Long serial FMA chains split across
// threads with LDS partial reduces.
// ---------------------------------------------------------------------------
__global__ __launch_bounds__(1024) void rgcn_finish(
    const int* __restrict__ gbins,
    const float* __restrict__ W1,    // [R][N][H]
    const float* __restrict__ root1, // [N][H]
    const float* __restrict__ b1,    // [H]
    const float* __restrict__ W2,    // [R][H][C]
    const float* __restrict__ root2, // [H][C]
    const float* __restrict__ b2,    // [C]
    float* __restrict__ out) {       // [N][C]
    __shared__ float cntf[NN][RR][NN];
    __shared__ float w1s[RR * NN * HH]; // 7168 floats
    __shared__ float w2s[RR * HH * CC]; // 8192 floats
    __shared__ float p1[NN][HH][4];
    __shared__ float h[NN][HH];
    __shared__ float hr[NN][RR][CC];    // hr[src][r][c]
    __shared__ float p2[NN][CC][8];
    __shared__ float o[NN][CC];

    const int t = threadIdx.x;
    const int BD = 1024;
    // stage weights (coalesced float4) + normalized counts, single barrier
    const float4* W1v = reinterpret_cast<const float4*>(W1);
    for (int i = t; i < RR * NN * HH / 4; i += BD)
        reinterpret_cast<float4*>(w1s)[i] = W1v[i];
    const float4* W2v = reinterpret_cast<const float4*>(W2);
    for (int i = t; i < RR * HH * CC / 4; i += BD)
        reinterpret_cast<float4*>(w2s)[i] = W2v[i];
    for (int i = t; i < NN * RR; i += BD) {
        int n = i / RR, r = i % RR;
        const int* gb = gbins + n * (RR * NN) + r * NN;
        int c[NN];
        int tot = 0;
#pragma unroll
        for (int s = 0; s < NN; ++s) { c[s] = gb[s]; tot += c[s]; }
        float inv = 1.0f / (float)(tot > 0 ? tot : 1);
#pragma unroll
        for (int s = 0; s < NN; ++s) cntf[n][r][s] = (float)c[s] * inv;
    }
    __syncthreads();

    // layer 1 partials: (n,j,q), q sums r in [16q,16q+16)
    for (int i = t; i < NN * HH * 4; i += BD) {
        int n = i >> 6;            // HH*4 = 64
        int j = (i >> 2) & (HH - 1);
        int q = i & 3;
        float acc = 0.0f;
        for (int r = q * 16; r < q * 16 + 16; ++r)
            for (int s = 0; s < NN; ++s)
                acc = fmaf(cntf[n][r][s], w1s[(r * NN + s) * HH + j], acc);
        p1[n][j][q] = acc;
    }
    __syncthreads();
    // layer 1 combine: h = relu(root1 + b1 + sum_q p1)
    for (int i = t; i < NN * HH; i += BD) {
        int n = i / HH, j = i % HH;
        float acc = root1[n * HH + j] + b1[j] +
                    p1[n][j][0] + p1[n][j][1] + p1[n][j][2] + p1[n][j][3];
        h[n][j] = fmaxf(acc, 0.0f);
    }
    __syncthreads();

    // hr[s][r][c] = sum_j h[s][j] * W2[r][j][c]
    for (int i = t; i < NN * RR * CC; i += BD) {
        int s = i / (RR * CC);
        int rem = i % (RR * CC);
        int r = rem / CC, c = rem % CC;
        float acc = 0.0f;
        for (int j = 0; j < HH; ++j)
            acc = fmaf(h[s][j], w2s[(r * HH + j) * CC + c], acc);
        hr[s][r][c] = acc;
    }
    __syncthreads();

    // layer 2 partials: (n,c,q), q sums r in [8q,8q+8); q==0 adds root+bias
    for (int i = t; i < NN * CC * 8; i += BD) {
        int n = i >> 6;            // CC*8 = 64
        int c = (i >> 3) & (CC - 1);
        int q = i & 7;
        float acc = 0.0f;
        for (int r = q * 8; r < q * 8 + 8; ++r)
            for (int s = 0; s < NN; ++s)
                acc = fmaf(cntf[n][r][s], hr[s][r][c], acc);
        if (q == 0) {
            for (int j = 0; j < HH; ++j)
                acc = fmaf(h[n][j], root2[j * CC + c], acc);
            acc += b2[c];
        }
        p2[n][c][q] = acc;
    }
    __syncthreads();
    // layer 2 combine
    for (int i = t; i < NN * CC; i += BD) {
        int n = i / CC, c = i % CC;
        float acc = 0.0f;
        for (int q = 0; q < 8; ++q) acc += p2[n][c][q];
        o[n][c] = acc;
    }
    __syncthreads();

    // row-wise log_softmax, one thread per node
    if (t < NN) {
        float m = -1e30f;
        for (int c = 0; c < CC; ++c) m = fmaxf(m, o[t][c]);
        float sum = 0.0f;
        for (int c = 0; c < CC; ++c) sum += __expf(o[t][c] - m);
        float lse = m + __logf(sum);
        for (int c = 0; c < CC; ++c) out[t * CC + c] = o[t][c] - lse;
    }
}

extern "C" void kernel_launch(void* const* d_in, const int* in_sizes, int n_in,
                              void* d_out, int out_size, void* d_ws, size_t ws_size,
                              hipStream_t stream) {
    // input order: x, edge_index, edge_type, W1, root1, b1, W2, root2, b2
    const int* edge_index = (const int*)d_in[1];
    const int* edge_type  = (const int*)d_in[2];
    const float* W1    = (const float*)d_in[3];
    const float* root1 = (const float*)d_in[4];
    const float* b1    = (const float*)d_in[5];
    const float* W2    = (const float*)d_in[6];
    const float* root2 = (const float*)d_in[7];
    const float* b2    = (const float*)d_in[8];
    float* out = (float*)d_out;

    const int E = in_sizes[2];              // num edges
    const int* src = edge_index;            // edge_index[0]
    const int* dst = edge_index + E;        // edge_index[1]

    int* part  = (int*)d_ws;                       // 256 * 3136 ints = 3.2 MB
    int* gbins = part + HIST_GRID * NBINS;         // 3136 ints

    rgcn_hist<<<HIST_GRID, HIST_BLOCK, 0, stream>>>(src, dst, edge_type, E, part);
    rgcn_reduce<<<49, 256, 0, stream>>>(part, gbins);
    rgcn_finish<<<1, 1024, 0, stream>>>(gbins, W1, root1, b1, W2, root2, b2, out);
}